// Round 8
// baseline (135.290 us; speedup 1.0000x reference)
//
#include <hip/hip_runtime.h>
#include <hip/hip_bf16.h>

// 2D DCT-II (4096x4096 fp32).  Round 7:
//   K1  = R4's dct_rows2 (row DCT, LDS FFT4096, 2 rows packed, 41 us)
//   K2a = column-pass step 1: per (b, col): z[a]=Y[sigma(64a+b)][col] (coalesced,
//         digit-rev folded into load), reg FFT64 (compile-time twiddles),
//         mid-twiddle W4096^{bq}, H -> ws
//   K2b = column-pass step 2: conj-split BEFORE FFT (A/B seq per wave),
//         reg FFT64, expk, coalesced store.  No LDS/barriers in K2a/K2b.
// Plan: K1(x->out) ; K2a(out->ws) ; K2b(ws->out).  d_ws needs 64 MB.

#define L 4096

__device__ __forceinline__ int SWZ(int e) {
    return e ^ (((e >> 4) ^ (e >> 8)) & 15);
}

__device__ __forceinline__ int digitrev12(int n) {
    int r = 0;
#pragma unroll
    for (int i = 0; i < 6; ++i) { r = (r << 2) | (n & 3); n >>= 2; }
    return r;
}

__device__ __forceinline__ float2 cmul(float2 a, float2 b) {
    return make_float2(a.x * b.x - a.y * b.y, a.x * b.y + a.y * b.x);
}

__device__ __forceinline__ void bfly4(float2& x0, float2& x1, float2& x2, float2& x3) {
    float t0x = x0.x + x2.x, t0y = x0.y + x2.y;
    float t1x = x0.x - x2.x, t1y = x0.y - x2.y;
    float t2x = x1.x + x3.x, t2y = x1.y + x3.y;
    float t3x = x1.x - x3.x, t3y = x1.y - x3.y;
    x0 = make_float2(t0x + t2x, t0y + t2y);
    x1 = make_float2(t1x + t3y, t1y - t3x);   // t1 + (-i)*t3
    x2 = make_float2(t0x - t2x, t0y - t2y);
    x3 = make_float2(t1x - t3y, t1y + t3x);   // t1 + (+i)*t3
}

// e^{-2*pi*i*m/64}; with compile-time m, folds to float literals.
__device__ __forceinline__ float2 W64C(int m) {
    constexpr float C[17] = {1.f, 0.995184726672197f, 0.980785280403230f,
        0.956940335732209f, 0.923879532511287f, 0.881921264348355f,
        0.831469612302545f, 0.773010453362737f, 0.707106781186548f,
        0.634393284163645f, 0.555570233019602f, 0.471396736825998f,
        0.382683432365090f, 0.290284677254462f, 0.195090322016128f,
        0.098017140329561f, 0.f};
    m &= 63;
    float c, s;
    if (m <= 16)      { c =  C[m];      s =  C[16 - m]; }
    else if (m <= 32) { c = -C[32 - m]; s =  C[m - 16]; }
    else if (m <= 48) { c = -C[m - 32]; s = -C[48 - m]; }
    else              { c =  C[64 - m]; s = -C[m - 48]; }
    return make_float2(c, -s);
}

// In-place radix-4 DIT FFT64 on registers.  Input: reg i = v[drev6(i)]
// (caller folds the digit reversal into its loads).  Output: natural order.
// All twiddles compile-time constants.
__device__ __forceinline__ void fft64r(float2* t) {
#pragma unroll
    for (int g = 0; g < 16; ++g)
        bfly4(t[4*g], t[4*g+1], t[4*g+2], t[4*g+3]);
#pragma unroll
    for (int j = 0; j < 4; ++j) {
#pragma unroll
        for (int g = 0; g < 4; ++g) {
            int base = 16*g + j;
            if (j) {
                t[base+4]  = cmul(t[base+4],  W64C(4*j));
                t[base+8]  = cmul(t[base+8],  W64C(8*j));
                t[base+12] = cmul(t[base+12], W64C(12*j));
            }
            bfly4(t[base], t[base+4], t[base+8], t[base+12]);
        }
    }
#pragma unroll
    for (int j = 0; j < 16; ++j) {
        if (j) {
            t[j+16] = cmul(t[j+16], W64C(j));
            t[j+32] = cmul(t[j+32], W64C(2*j));
            t[j+48] = cmul(t[j+48], W64C(3*j));
        }
        bfly4(t[j], t[j+16], t[j+32], t[j+48]);
    }
}

// ---------------- K1: row DCT (R4 structure, unchanged) ----------------

template <int Q>
__device__ __forceinline__ void stage_pair(float2* lds, int t) {
    const int j = t & (Q - 1);
    const int G = t / Q;
    const int base = G * 16 * Q + j;

    float2 v[4][4];
#pragma unroll
    for (int b = 0; b < 4; ++b)
#pragma unroll
        for (int a = 0; a < 4; ++a)
            v[a][b] = lds[SWZ(base + (a + 4 * b) * Q)];

    if (Q > 1) {
        float c1, s1;
        __sincosf((float)j * (-6.2831853071795864769f / (4.0f * (float)Q)), &s1, &c1);
        float2 w1 = make_float2(c1, s1);
        float2 w2 = cmul(w1, w1);
        float2 w3 = cmul(w2, w1);
#pragma unroll
        for (int b = 0; b < 4; ++b) {
            v[1][b] = cmul(v[1][b], w1);
            v[2][b] = cmul(v[2][b], w2);
            v[3][b] = cmul(v[3][b], w3);
        }
    }
#pragma unroll
    for (int b = 0; b < 4; ++b) bfly4(v[0][b], v[1][b], v[2][b], v[3][b]);

    float2 u;
    if (Q == 1) {
        u = make_float2(1.0f, 0.0f);
    } else {
        float cu, su;
        __sincosf((float)j * (-6.2831853071795864769f / (16.0f * (float)Q)), &su, &cu);
        u = make_float2(cu, su);
    }
    const float2 E = make_float2(0.92387953251128674f, -0.38268343236508977f);
    float2 w = u;
#pragma unroll
    for (int a = 0; a < 4; ++a) {
        if (!(Q == 1 && a == 0)) {
            float2 W2 = cmul(w, w);
            float2 W3 = cmul(W2, w);
            v[a][1] = cmul(v[a][1], w);
            v[a][2] = cmul(v[a][2], W2);
            v[a][3] = cmul(v[a][3], W3);
        }
        bfly4(v[a][0], v[a][1], v[a][2], v[a][3]);
        if (a < 3) w = cmul(w, E);
    }

#pragma unroll
    for (int b = 0; b < 4; ++b)
#pragma unroll
        for (int a = 0; a < 4; ++a)
            lds[SWZ(base + (a + 4 * b) * Q)] = v[a][b];
}

__global__ __launch_bounds__(256)
void dct_rows2_kernel(const float* __restrict__ in, float* __restrict__ out) {
    __shared__ float2 lds[L];   // 32 KB

    const int r0 = blockIdx.x * 2;
    const int t = threadIdx.x;
    const float* rowA = in + (size_t)r0 * L;
    const float* rowB = rowA + L;

#pragma unroll
    for (int w = 0; w < 8; ++w) {
        int n = w * 256 + t;
        float2 fa = *reinterpret_cast<const float2*>(&rowA[2 * n]);
        float2 fb = *reinterpret_cast<const float2*>(&rowB[2 * n]);
        int p = digitrev12(n);
        lds[SWZ(p)]        = make_float2(fa.x, fb.x);
        lds[SWZ(4095 - p)] = make_float2(fa.y, fb.y);
    }
    __syncthreads();

    stage_pair<1>(lds, t);
    __syncthreads();
    stage_pair<16>(lds, t);
    __syncthreads();
    stage_pair<256>(lds, t);
    __syncthreads();

    float* outA = out + (size_t)r0 * L;
    float* outB = outA + L;
#pragma unroll
    for (int w = 0; w < 16; ++w) {
        int k = w * 256 + t;
        float2 Zk = lds[SWZ(k)];
        int m = (L - k) & (L - 1);
        float2 Zm = lds[SWZ(m)];

        float vax = 0.5f * (Zk.x + Zm.x);
        float vay = 0.5f * (Zk.y - Zm.y);
        float vbx = 0.5f * (Zk.y + Zm.y);
        float vby = 0.5f * (Zm.x - Zk.x);

        float th = (float)k * 3.8349519697141029e-4f;   // pi/8192
        float sk, ck;
        __sincosf(th, &sk, &ck);
        outA[k] = vax * ck + vay * sk;
        outB[k] = vbx * ck + vby * sk;
    }
}

// ---------------- K2a: column pass, step 1 ----------------
// Packs columns (128T+c, 128T+64+c) as complex.  Per wave: fixed b.
// z[reg i] = v[64*drev(i)+b] loaded straight from Y (coalesced 256B).
// After FFT64 (natural q), z[q] *= W4096^{b q}; store H[q][b][T][c] to ws.
__global__ __launch_bounds__(256)
void fft64_col_a(const float* __restrict__ Y, float* __restrict__ ws) {
    const int c = threadIdx.x & 63;
    const int w = threadIdx.x >> 6;
    const int b = blockIdx.x * 4 + w;       // 0..63
    const int T = blockIdx.y;               // 0..31
    const int ca = T * 128 + c;
    const int cb = ca + 64;

    float2 z[64];
#pragma unroll
    for (int i = 0; i < 64; ++i) {
        const int a = ((i & 3) << 4) | (i & 12) | (i >> 4);   // drev6(i)
        int j = 64 * a + b;
        int row = (a < 32) ? (2 * j) : (8191 - 2 * j);        // Makhoul sigma
        const float* rp = Y + (size_t)row * L;
        z[i] = make_float2(rp[ca], rp[cb]);
    }

    fft64r(z);

    // mid twiddle: z[q] *= e^{-2 pi i b q / 4096}, wave-uniform chain
    const float ang = (float)b * -1.5339807878856412e-3f;     // -2pi b/4096
    float2 m1; __sincosf(ang, &m1.y, &m1.x);
#pragma unroll
    for (int q0 = 0; q0 < 64; q0 += 8) {
        float2 wv;
        if (q0 == 0) wv = make_float2(1.0f, 0.0f);
        else         __sincosf(ang * (float)q0, &wv.y, &wv.x);
#pragma unroll
        for (int d = 0; d < 8; ++d) {
            int q = q0 + d;
            if (q) z[q] = cmul(z[q], wv);
            if (d < 7) wv = cmul(wv, m1);
        }
    }

    float2* wp = reinterpret_cast<float2*>(ws) + (size_t)b * 2048 + (size_t)T * 64 + c;
#pragma unroll
    for (int q = 0; q < 64; ++q)
        wp[(size_t)q * 131072] = z[q];
}

// ---------------- K2b: column pass, step 2 ----------------
// Per wave: fixed q, A-or-B sequence.  Conj-split BEFORE the FFT:
//   Aseq[b] = 0.5*(H[q][b] + conj(H[q'][b])*fac_b),  q'=(64-q)&63,
//   Bseq[b] = -0.5i*(H[q][b] - conj(H[q'][b])*fac_b),
//   fac_b = W64^b for q>=1, 1 for q==0.   F/G[64p+q] = FFT64_b{seq}[p].
// out[64p+q][col] = Re(F * e^{-i pi k/8192}).
__global__ __launch_bounds__(256)
void fft64_col_b(const float* __restrict__ wsf, float* __restrict__ out) {
    const int c  = threadIdx.x & 63;
    const int w  = threadIdx.x >> 6;
    const int qa = blockIdx.x;              // 0..31
    const int T  = blockIdx.y;              // 0..31
    const int q  = (w < 2) ? qa : ((qa == 0) ? 32 : 64 - qa);
    const int isB = w & 1;
    const int qp = (q == 0) ? 0 : ((64 - q) & 63);
    const bool selfp = (qp == q);

    const float2* wsc = reinterpret_cast<const float2*>(wsf);
    const float2* hq = wsc + (size_t)q  * 131072 + (size_t)T * 64 + c;
    const float2* hp = wsc + (size_t)qp * 131072 + (size_t)T * 64 + c;

    float2 t[64];
#pragma unroll
    for (int i = 0; i < 64; ++i) {
        const int bb = ((i & 3) << 4) | (i & 12) | (i >> 4);  // drev6(i)
        float2 a0 = hq[(size_t)bb * 2048];
        float2 p0 = selfp ? a0 : hp[(size_t)bb * 2048];
        float2 pc = make_float2(p0.x, -p0.y);
        float2 m  = (q == 0) ? pc : cmul(pc, W64C(bb));
        if (!isB) {
            t[i] = make_float2(0.5f * (a0.x + m.x), 0.5f * (a0.y + m.y));
        } else {
            float vx = a0.x - m.x, vy = a0.y - m.y;
            t[i] = make_float2(0.5f * vy, -0.5f * vx);        // -i/2 * v
        }
    }

    fft64r(t);

    const int col = T * 128 + (isB ? 64 : 0) + c;
    float* op = out + col;
    const float2 M = make_float2(0.99969881869620425f, 0.024541228522912288f); // e^{+i pi/128} as (cos,sin)
    float2 e;
#pragma unroll
    for (int p = 0; p < 64; ++p) {
        if ((p & 15) == 0)
            __sincosf((float)(64 * p + q) * 3.8349519697141029e-4f, &e.y, &e.x);
        op[(size_t)(64 * p + q) * L] = t[p].x * e.x + t[p].y * e.y;
        e = cmul(e, M);
    }
}

extern "C" void kernel_launch(void* const* d_in, const int* in_sizes, int n_in,
                              void* d_out, int out_size, void* d_ws, size_t ws_size,
                              hipStream_t stream) {
    const float* x = (const float*)d_in[0];
    float* out = (float*)d_out;
    float* ws  = (float*)d_ws;   // needs 64 MB

    dct_rows2_kernel<<<L / 2, 256, 0, stream>>>(x, out);        // rows: x -> Y(out)
    fft64_col_a<<<dim3(16, 32), 256, 0, stream>>>(out, ws);     // Y -> H(ws)
    fft64_col_b<<<dim3(32, 32), 256, 0, stream>>>(ws, out);     // H -> final(out)
}